// Round 3
// baseline (1087.782 us; speedup 1.0000x reference)
//
#include <hip/hip_runtime.h>
#include <hip/hip_bf16.h>
#include <hip/hip_fp16.h>

// Problem constants
#define B_    256
#define TR    512
#define P_    128
#define H_    128
#define NG    384      // 3*H
#define KI    256      // 2*P
#define TA    64
#define PSTD  32
#define PSTAT 16
#define HH    64       // HEAD_H
#define FDIM  176      // H + P_STD + P_STATIC

#define NB    8            // batches per scan block (MFMA N-cols used)
#define NSCAN (B_/NB)      // 32 scan blocks

typedef __attribute__((ext_vector_type(8))) short short8;
typedef __attribute__((ext_vector_type(4))) float f32x4;
typedef _Float16 f16;
typedef __attribute__((ext_vector_type(8))) _Float16 f16x8;

// ---- helpers ----
__device__ __forceinline__ float bf2f(ushort u) {
    union { uint i; float f; } v; v.i = ((uint)u) << 16; return v.f;
}
__device__ __forceinline__ ushort f2bf(float f) {
    union { float f; uint u; } v; v.f = f;
    uint u = v.u;
    uint r = (u + 0x7fffu + ((u >> 16) & 1u)) >> 16;  // RTNE
    return (ushort)r;
}
__device__ __forceinline__ float bflo(uint u) {
    union { uint i; float f; } v; v.i = u << 16; return v.f;
}
__device__ __forceinline__ float bfhi(uint u) {
    union { uint i; float f; } v; v.i = u & 0xffff0000u; return v.f;
}
__device__ __forceinline__ float tanhf_fast(float x) {
    float ax = fabsf(x);
    float e = __expf(-2.f * ax);
    float r = (1.f - e) / (1.f + e);
    return copysignf(r, x);
}
// branch-free scan transcendentals (v_exp + v_rcp)
__device__ __forceinline__ float sigf2(float x) {
    return __builtin_amdgcn_rcpf(1.f + __expf(-x));
}
__device__ __forceinline__ float tanh2(float x) {
    // tanh(x) = 1 - 2/(exp(2x)+1); saturates correctly at +/-inf, no NaN
    return 1.f - 2.f * __builtin_amdgcn_rcpf(1.f + __expf(2.f * x));
}
// LDS-only barrier: does NOT drain vmcnt (keeps gate prefetch in flight).
__device__ __forceinline__ void bar_lds() {
    __asm__ volatile("s_waitcnt lgkmcnt(0)\n\ts_barrier" ::: "memory");
}

// ---------------------------------------------------------------------------
// Kernel 0: convert Wih, Wd to bf16; fold bhh_{r,z} into bih -> bihc.
// ---------------------------------------------------------------------------
__global__ __launch_bounds__(256) void k_convert(
    const float* __restrict__ Wih, const float* __restrict__ Wd,
    const float* __restrict__ bih, const float* __restrict__ bhh,
    ushort* __restrict__ wih_b, ushort* __restrict__ wd_b,
    float* __restrict__ bihc)
{
    int i = blockIdx.x * 256 + threadIdx.x;
    if (i < NG * KI) wih_b[i] = f2bf(Wih[i]);
    if (i < H_ * P_) wd_b[i]  = f2bf(Wd[i]);
    if (i < NG) bihc[i] = bih[i] + (i < 2 * H_ ? bhh[i] : 0.f);
}

// ---------------------------------------------------------------------------
// Kernel 1: fused elementwise + GEMM (MFMA bf16 16x16x32). [unchanged]
// ---------------------------------------------------------------------------
#define SA 392   // padded LDS row stride in bf16 elems (also >= 384 for staging)

__global__ __launch_bounds__(256, 2) void k_gemm(
    const float* __restrict__ X, const float* __restrict__ M,
    const float* __restrict__ DT, const float* __restrict__ xmean,
    const ushort* __restrict__ wih_b, const ushort* __restrict__ wd_b,
    const float* __restrict__ bih, const float* __restrict__ bd,
    ushort* __restrict__ gi_ws, ushort* __restrict__ htil_ws,
    float* __restrict__ delta_ws)
{
    __shared__ __align__(16) ushort sA[64 * SA];   // 50176 B; reused for staging
    const int tid = threadIdx.x;
    const long r0 = (long)blockIdx.x * 64;

    // ---- build A tile (64 rows x [x_dec|m|x_hat]) + delta (coalesced f32) ----
    #pragma unroll 4
    for (int i = 0; i < 32; ++i) {
        int idx = i * 256 + tid;
        int rl = idx >> 7, k = idx & 127;
        long g = (r0 + rl) * 128 + k;
        float x = X[g], m = M[g], dt = DT[g], xm = xmean[k];
        float delta = 1.f / (1.f + __expf(dt));   // sigmoid(-dt)
        float xh = m * x + (1.f - m) * xm;
        float xd = m * x + (1.f - m) * (delta * xh + (1.f - delta) * xm);
        sA[rl * SA + k]       = f2bf(xd);
        sA[rl * SA + 128 + k] = f2bf(m);
        sA[rl * SA + 256 + k] = f2bf(xh);
        delta_ws[g] = delta;
    }
    __syncthreads();

    const int wv   = tid >> 6;        // wave 0..3 -> gi col slice [96w,96w+96)
    const int lane = tid & 63;
    const int l16  = lane & 15;       // A row idx / B col idx / C col idx
    const int q    = lane >> 4;       // quad: A k-offset q*8 / C rows q*4+reg

    // ---- gi: acc[rt][nt], rt = row-tile (16 rows), nt = col-tile in slice ----
    f32x4 acc[4][6];
    #pragma unroll
    for (int rt = 0; rt < 4; ++rt)
        #pragma unroll
        for (int nt = 0; nt < 6; ++nt) acc[rt][nt] = (f32x4){0.f, 0.f, 0.f, 0.f};

    const int nb = 96 * wv;
    #pragma unroll
    for (int ks = 0; ks < 8; ++ks) {
        short8 a[4];
        #pragma unroll
        for (int rt = 0; rt < 4; ++rt)
            a[rt] = *(const short8*)&sA[(rt * 16 + l16) * SA + ks * 32 + q * 8];
        #pragma unroll
        for (int nt = 0; nt < 6; ++nt) {
            const short8 b = *(const short8*)&wih_b[(size_t)(nb + nt * 16 + l16) * KI + ks * 32 + q * 8];
            #pragma unroll
            for (int rt = 0; rt < 4; ++rt)
                acc[rt][nt] = __builtin_amdgcn_mfma_f32_16x16x32_bf16(a[rt], b, acc[rt][nt], 0, 0, 0);
        }
    }

    // ---- htil: acc2[rt][nt2], col slice [32w,32w+32), K=128 (A cols 256+) ----
    f32x4 acc2[4][2];
    #pragma unroll
    for (int rt = 0; rt < 4; ++rt)
        #pragma unroll
        for (int nt = 0; nt < 2; ++nt) acc2[rt][nt] = (f32x4){0.f, 0.f, 0.f, 0.f};

    const int nb2 = 32 * wv;
    #pragma unroll
    for (int ks = 0; ks < 4; ++ks) {
        short8 a[4];
        #pragma unroll
        for (int rt = 0; rt < 4; ++rt)
            a[rt] = *(const short8*)&sA[(rt * 16 + l16) * SA + 256 + ks * 32 + q * 8];
        #pragma unroll
        for (int nt = 0; nt < 2; ++nt) {
            const short8 b = *(const short8*)&wd_b[(size_t)(nb2 + nt * 16 + l16) * P_ + ks * 32 + q * 8];
            #pragma unroll
            for (int rt = 0; rt < 4; ++rt)
                acc2[rt][nt] = __builtin_amdgcn_mfma_f32_16x16x32_bf16(a[rt], b, acc2[rt][nt], 0, 0, 0);
        }
    }

    __syncthreads();   // all sA reads done; safe to overwrite with staging

    // ---- stage gi (bf16, [row][n] unpadded 64x384) into sA region ----
    ushort* sOut = sA;
    #pragma unroll
    for (int nt = 0; nt < 6; ++nt) {
        const int n = nb + nt * 16 + l16;
        const float bi = bih[n];
        #pragma unroll
        for (int rt = 0; rt < 4; ++rt) {
            #pragma unroll
            for (int reg = 0; reg < 4; ++reg) {
                int row = rt * 16 + q * 4 + reg;
                sOut[row * NG + n] = f2bf(acc[rt][nt][reg] + bi);
            }
        }
    }
    __syncthreads();

    // ---- coalesced contiguous store: 64*384 bf16 = 3072 uint4 ----
    {
        uint4* dst = (uint4*)(gi_ws + (size_t)r0 * NG);
        const uint4* src = (const uint4*)sOut;
        #pragma unroll
        for (int i = 0; i < 12; ++i) dst[tid + 256 * i] = src[tid + 256 * i];
    }
    __syncthreads();   // uint4 LDS reads retired; safe to restage

    // ---- stage htil (bf16, [row][n] 64x128) ----
    #pragma unroll
    for (int nt = 0; nt < 2; ++nt) {
        const int n = nb2 + nt * 16 + l16;
        const float bi = bd[n];
        #pragma unroll
        for (int rt = 0; rt < 4; ++rt) {
            #pragma unroll
            for (int reg = 0; reg < 4; ++reg) {
                int row = rt * 16 + q * 4 + reg;
                sOut[row * P_ + n] = f2bf(tanhf_fast(acc2[rt][nt][reg] + bi));
            }
        }
    }
    __syncthreads();

    // ---- coalesced store: 64*128 bf16 = 1024 uint4 ----
    {
        uint4* dst = (uint4*)(htil_ws + (size_t)r0 * P_);
        const uint4* src = (const uint4*)sOut;
        #pragma unroll
        for (int i = 0; i < 4; ++i) dst[tid + 256 * i] = src[tid + 256 * i];
    }
}

// ---------------------------------------------------------------------------
// Kernel 2: recurrent scan v5 — MFMA-batched, 4-deep prefetch rotation.
//   v4 post-mortem: 2-buffer rotation made the steady-state s_waitcnt for
//   htil/delta a FULL vmcnt(0) drain every step (loads issued one step
//   earlier with nothing after them) -> ~3164 cy/step, all pipes idle.
//   v5: 4 register buffers (gA..gD); each STEP refills its consumed buffer
//   4 steps ahead. Steady-state waits become vmcnt(~30) for gates and
//   vmcnt(~20) for htil/delta -> 3 steps of compute cover the scattered
//   load latency. Max outstanding VMEM/wave = 40 < 63 (vmcnt width).
// ---------------------------------------------------------------------------

#define DECLB(PFX) uint2 PFX##_r0, PFX##_r1, PFX##_z0, PFX##_z1,            \
                         PFX##_n0, PFX##_n1, PFX##_h0, PFX##_h1;            \
                   float4 PFX##_d0, PFX##_d1;

#define LOADG(PFX, T) if (act) {                                            \
    const ushort* gp = gptr + (size_t)(T) * NG;                             \
    const ushort* hp = hptr + (size_t)(T) * P_;                             \
    const float*  dp = dptr + (size_t)(T) * P_;                             \
    PFX##_r0 = *(const uint2*)(gp + j0);                                    \
    PFX##_r1 = *(const uint2*)(gp + j0 + 16);                               \
    PFX##_z0 = *(const uint2*)(gp + 128 + j0);                              \
    PFX##_z1 = *(const uint2*)(gp + 128 + j0 + 16);                         \
    PFX##_n0 = *(const uint2*)(gp + 256 + j0);                              \
    PFX##_n1 = *(const uint2*)(gp + 256 + j0 + 16);                         \
    PFX##_h0 = *(const uint2*)(hp + j0);                                    \
    PFX##_h1 = *(const uint2*)(hp + j0 + 16);                               \
    PFX##_d0 = *(const float4*)(dp + j0);                                   \
    PFX##_d1 = *(const float4*)(dp + j0 + 16);                              \
}

#define STEP(T, BC, BN, PC, PN) {                                           \
    bar_lds();                                                              \
    f16x8 bf[4];                                                            \
    _Pragma("unroll")                                                       \
    for (int ks = 0; ks < 4; ++ks)                                          \
        bf[ks] = *(const f16x8*)&h_lds[PC][bb][ks * 32 + q * 8];            \
    f32x4 ac[3][2];                                                         \
    ac[0][0] = (f32x4){bflo(BC##_r0.x), bfhi(BC##_r0.x), bflo(BC##_r0.y), bfhi(BC##_r0.y)}; \
    ac[0][1] = (f32x4){bflo(BC##_r1.x), bfhi(BC##_r1.x), bflo(BC##_r1.y), bfhi(BC##_r1.y)}; \
    ac[1][0] = (f32x4){bflo(BC##_z0.x), bfhi(BC##_z0.x), bflo(BC##_z0.y), bfhi(BC##_z0.y)}; \
    ac[1][1] = (f32x4){bflo(BC##_z1.x), bfhi(BC##_z1.x), bflo(BC##_z1.y), bfhi(BC##_z1.y)}; \
    ac[2][0] = (f32x4){bhn[0][0], bhn[0][1], bhn[0][2], bhn[0][3]};         \
    ac[2][1] = (f32x4){bhn[1][0], bhn[1][1], bhn[1][2], bhn[1][3]};         \
    _Pragma("unroll")                                                       \
    for (int ks = 0; ks < 4; ++ks) {                                        \
        _Pragma("unroll")                                                   \
        for (int g = 0; g < 3; ++g) {                                       \
            ac[g][0] = __builtin_amdgcn_mfma_f32_16x16x32_f16(aF[g][0][ks], bf[ks], ac[g][0], 0, 0, 0); \
            ac[g][1] = __builtin_amdgcn_mfma_f32_16x16x32_f16(aF[g][1][ks], bf[ks], ac[g][1], 0, 0, 0); \
        }                                                                   \
    }                                                                       \
    if (act) {                                                              \
        _Pragma("unroll")                                                   \
        for (int jt = 0; jt < 2; ++jt) {                                    \
            uint2 gnv = jt ? BC##_n1 : BC##_n0;                             \
            uint2 htv = jt ? BN##_h1 : BN##_h0;                             \
            float4 dlv = jt ? BN##_d1 : BN##_d0;                            \
            float gn_[4] = {bflo(gnv.x), bfhi(gnv.x), bflo(gnv.y), bfhi(gnv.y)}; \
            float ht_[4] = {bflo(htv.x), bfhi(htv.x), bflo(htv.y), bfhi(htv.y)}; \
            float dl_[4] = {dlv.x, dlv.y, dlv.z, dlv.w};                    \
            float hnv[4];                                                   \
            _Pragma("unroll")                                               \
            for (int r = 0; r < 4; ++r) {                                   \
                float rg = sigf2(ac[0][jt][r]);                             \
                float zg = sigf2(ac[1][jt][r]);                             \
                float np = gn_[r] + rg * ac[2][jt][r];                      \
                float ng = tanh2(np);                                       \
                float hn = ng + zg * (hpre[jt][r] - ng);                    \
                hnv[r] = hn;                                                \
                hpre[jt][r] = ht_[r] + dl_[r] * (hn - ht_[r]);              \
            }                                                               \
            *(float4*)&Hraw[(rowb + (T)) * P_ + j0 + jt * 16] =             \
                make_float4(hnv[0], hnv[1], hnv[2], hnv[3]);                \
            f16 p0 = (f16)hpre[jt][0], p1 = (f16)hpre[jt][1],               \
                p2 = (f16)hpre[jt][2], p3 = (f16)hpre[jt][3];               \
            union { f16 h[4]; uint2 u; } pk = {{p0, p1, p2, p3}};           \
            *(uint2*)&h_lds[PN][bb][j0 + jt * 16] = pk.u;                   \
        }                                                                   \
    }                                                                       \
    if ((T) + 4 < TR) LOADG(BC, (T) + 4);                                   \
}

__global__ __launch_bounds__(256, 1) void k_scan(
    const ushort* __restrict__ gi_ws, const ushort* __restrict__ htil_ws,
    const float* __restrict__ delta_ws, const float* __restrict__ Whh,
    const float* __restrict__ bhh, float* __restrict__ Hraw)
{
    __shared__ __align__(16) f16 h_lds[2][16][136];   // 8704 B; +8 pad/row

    const int tid  = threadIdx.x;
    const int w    = tid >> 6;          // wave 0..3 -> j slice [32w, 32w+32)
    const int lane = tid & 63;
    const int bb   = lane & 15;         // B col = batch (0..7 real)
    const int q    = lane >> 4;         // k-chunk / C row group
    const bool act = bb < NB;
    const int bbw  = bb & (NB - 1);
    const int b0   = blockIdx.x * NB;
    const int j0   = w * 32 + q * 4;    // jt adds +16

    // zero LDS (covers parity-1 and the unused batch cols 8..15)
    for (int i = tid; i < 2 * 16 * 136; i += 256) ((f16*)h_lds)[i] = (f16)0.f;

    // Whh A-fragments: load f32, convert to f16 in-register.
    f16x8 aF[3][2][4];
    #pragma unroll
    for (int g = 0; g < 3; ++g)
        #pragma unroll
        for (int jt = 0; jt < 2; ++jt) {
            const float* wr = Whh + (size_t)(g * 128 + w * 32 + jt * 16 + bb) * 128;
            #pragma unroll
            for (int ks = 0; ks < 4; ++ks) {
                float4 a = *(const float4*)(wr + ks * 32 + q * 8);
                float4 c = *(const float4*)(wr + ks * 32 + q * 8 + 4);
                f16x8 v;
                v[0] = (f16)a.x; v[1] = (f16)a.y; v[2] = (f16)a.z; v[3] = (f16)a.w;
                v[4] = (f16)c.x; v[5] = (f16)c.y; v[6] = (f16)c.z; v[7] = (f16)c.w;
                aF[g][jt][ks] = v;
            }
        }

    float bhn[2][4];
    #pragma unroll
    for (int jt = 0; jt < 2; ++jt)
        #pragma unroll
        for (int r = 0; r < 4; ++r)
            bhn[jt][r] = bhh[256 + j0 + jt * 16 + r];

    const long rowb = (long)(b0 + bbw) * TR;
    const ushort* gptr = gi_ws   + rowb * NG;
    const ushort* hptr = htil_ws + rowb * P_;
    const float*  dptr = delta_ws + rowb * P_;

    DECLB(gA) DECLB(gB) DECLB(gC) DECLB(gD)

    LOADG(gA, 0);
    LOADG(gB, 1);
    LOADG(gC, 2);
    LOADG(gD, 3);

    float hpre[2][4] = {{0.f, 0.f, 0.f, 0.f}, {0.f, 0.f, 0.f, 0.f}};

    __syncthreads();   // zero-init visible before h_pre(0) writes

    // h_pre(0) = (1 - d0) * htil0   (h(-1) = 0)
    if (act) {
        #pragma unroll
        for (int jt = 0; jt < 2; ++jt) {
            uint2 htv = jt ? gA_h1 : gA_h0;
            float4 dlv = jt ? gA_d1 : gA_d0;
            float ht_[4] = {bflo(htv.x), bfhi(htv.x), bflo(htv.y), bfhi(htv.y)};
            float dl_[4] = {dlv.x, dlv.y, dlv.z, dlv.w};
            #pragma unroll
            for (int r = 0; r < 4; ++r)
                hpre[jt][r] = ht_[r] - dl_[r] * ht_[r];
            f16 p0 = (f16)hpre[jt][0], p1 = (f16)hpre[jt][1],
                p2 = (f16)hpre[jt][2], p3 = (f16)hpre[jt][3];
            union { f16 h[4]; uint2 u; } pk = {{p0, p1, p2, p3}};
            *(uint2*)&h_lds[0][bb][j0 + jt * 16] = pk.u;
        }
    }

    for (int t = 0; t < TR; t += 4) {
        STEP(t,     gA, gB, 0, 1);
        STEP(t + 1, gB, gC, 1, 0);
        STEP(t + 2, gC, gD, 0, 1);
        STEP(t + 3, gD, gA, 1, 0);
    }
}

// ---------------------------------------------------------------------------
// Kernel 3: head. [unchanged]
// ---------------------------------------------------------------------------
__global__ __launch_bounds__(256) void k_head(
    const float* __restrict__ Hraw, const float* __restrict__ STD,
    const float* __restrict__ Z, const int* __restrict__ idx_map,
    const float* __restrict__ W1, const float* __restrict__ b1,
    const float* __restrict__ W2,
    float* __restrict__ eta, float* __restrict__ Hagg,
    float* __restrict__ mask_out)
{
    __shared__ float sW1[HH * FDIM];
    __shared__ float sb1[HH], sW2[HH];
    __shared__ float spart[TA][4];

    const int tid = threadIdx.x, b = blockIdx.x;
    for (int i = tid; i < HH * FDIM; i += 256) sW1[i] = W1[i];
    if (tid < HH) { sb1[tid] = b1[tid]; sW2[tid] = W2[tid]; }
    __syncthreads();

    const int s = tid >> 2, p = tid & 3;
    const int idx = idx_map[b * TA + s];
    const int valid = idx >= 0;
    const int tt = valid ? idx : 0;
    const float* hrow = Hraw + ((long)b * TR + tt) * H_;

    float acc[16];
    #pragma unroll
    for (int uu = 0; uu < 16; ++uu) acc[uu] = sb1[p * 16 + uu];

    for (int f = 0; f < FDIM; ++f) {
        float feat;
        if (f < H_)              feat = valid ? hrow[f] : 0.f;
        else if (f < H_ + PSTD)  feat = STD[((long)b * TA + s) * PSTD + (f - H_)];
        else                     feat = Z[b * PSTAT + (f - H_ - PSTD)];
        #pragma unroll
        for (int uu = 0; uu < 16; ++uu)
            acc[uu] += feat * sW1[(p * 16 + uu) * FDIM + f];
    }

    float pe = 0.f;
    #pragma unroll
    for (int uu = 0; uu < 16; ++uu) {
        float a = acc[uu];
        pe += (a > 0.f ? a : 0.f) * sW2[p * 16 + uu];
    }
    spart[s][p] = pe;

    for (int e = 0; e < 32; ++e) {
        int ee = p * 32 + e;
        Hagg[((long)b * TA + s) * H_ + ee] = valid ? hrow[ee] : 0.f;
    }
    if (p == 0) mask_out[b * TA + s] = valid ? 1.f : 0.f;

    __syncthreads();
    if (tid < TA)
        eta[b * TA + tid] = spart[tid][0] + spart[tid][1] + spart[tid][2] + spart[tid][3];
}

// ---------------------------------------------------------------------------
extern "C" void kernel_launch(void* const* d_in, const int* in_sizes, int n_in,
                              void* d_out, int out_size, void* d_ws, size_t ws_size,
                              hipStream_t stream)
{
    const float* X     = (const float*)d_in[0];
    const float* M     = (const float*)d_in[1];
    const float* DT    = (const float*)d_in[2];
    const float* STD   = (const float*)d_in[3];
    const float* Z     = (const float*)d_in[4];
    const int*   idxm  = (const int*)  d_in[5];
    const float* xmean = (const float*)d_in[6];
    const float* Wd    = (const float*)d_in[7];
    const float* bd    = (const float*)d_in[8];
    const float* Wih   = (const float*)d_in[9];
    const float* bih   = (const float*)d_in[10];
    const float* Whh   = (const float*)d_in[11];
    const float* bhh   = (const float*)d_in[12];
    const float* W1    = (const float*)d_in[13];
    const float* b1    = (const float*)d_in[14];
    const float* W2    = (const float*)d_in[15];

    const long RROWS = (long)B_ * TR;   // 131072
    char* ws = (char*)d_ws;
    size_t off = 0;
    ushort* gi_ws   = (ushort*)(ws + off); off += (size_t)RROWS * NG * 2;
    ushort* htil_ws = (ushort*)(ws + off); off += (size_t)RROWS * P_ * 2;
    float*  delta_ws= (float*) (ws + off); off += (size_t)RROWS * P_ * 4;
    ushort* wih_b   = (ushort*)(ws + off); off += (size_t)NG * KI * 2;
    ushort* wd_b    = (ushort*)(ws + off); off += (size_t)H_ * P_ * 2;
    float*  bihc    = (float*) (ws + off); off += (size_t)NG * 4;

    float* out   = (float*)d_out;
    float* eta   = out;                                  // [256,64]
    float* Hraw  = out + 16384;                          // [256,512,128]
    float* Hagg  = out + 16384 + (long)B_ * TR * H_;     // [256,64,128]
    float* maskO = Hagg + (long)B_ * TA * H_;            // [256,64]

    hipLaunchKernelGGL(k_convert, dim3(384), dim3(256), 0, stream,
                       Wih, Wd, bih, bhh, wih_b, wd_b, bihc);
    hipLaunchKernelGGL(k_gemm, dim3(2048), dim3(256), 0, stream,
                       X, M, DT, xmean, wih_b, wd_b, bihc, bd,
                       gi_ws, htil_ws, delta_ws);
    hipLaunchKernelGGL(k_scan, dim3(NSCAN), dim3(256), 0, stream,
                       gi_ws, htil_ws, delta_ws, Whh, bhh, Hraw);
    hipLaunchKernelGGL(k_head, dim3(256), dim3(256), 0, stream,
                       Hraw, STD, Z, idxm, W1, b1, W2, eta, Hagg, maskO);
}

// Round 4
// 1084.993 us; speedup vs baseline: 1.0026x; 1.0026x over previous
//
#include <hip/hip_runtime.h>
#include <hip/hip_bf16.h>
#include <hip/hip_fp16.h>

// Problem constants
#define B_    256
#define TR    512
#define P_    128
#define H_    128
#define NG    384      // 3*H
#define KI    256      // 2*P
#define TA    64
#define PSTD  32
#define PSTAT 16
#define HH    64       // HEAD_H
#define FDIM  176      // H + P_STD + P_STATIC

#define NB    8            // batches per scan block (MFMA N-cols used)
#define NSCAN (B_/NB)      // 32 scan blocks

typedef __attribute__((ext_vector_type(8))) short short8;
typedef __attribute__((ext_vector_type(4))) float f32x4;
typedef _Float16 f16;
typedef __attribute__((ext_vector_type(8))) _Float16 f16x8;

// ---- helpers ----
__device__ __forceinline__ float bf2f(ushort u) {
    union { uint i; float f; } v; v.i = ((uint)u) << 16; return v.f;
}
__device__ __forceinline__ ushort f2bf(float f) {
    union { float f; uint u; } v; v.f = f;
    uint u = v.u;
    uint r = (u + 0x7fffu + ((u >> 16) & 1u)) >> 16;  // RTNE
    return (ushort)r;
}
__device__ __forceinline__ float bflo(uint u) {
    union { uint i; float f; } v; v.i = u << 16; return v.f;
}
__device__ __forceinline__ float bfhi(uint u) {
    union { uint i; float f; } v; v.i = u & 0xffff0000u; return v.f;
}
__device__ __forceinline__ float tanhf_fast(float x) {
    float ax = fabsf(x);
    float e = __expf(-2.f * ax);
    float r = (1.f - e) / (1.f + e);
    return copysignf(r, x);
}
// branch-free scan transcendentals (v_exp + v_rcp)
__device__ __forceinline__ float sigf2(float x) {
    return __builtin_amdgcn_rcpf(1.f + __expf(-x));
}
__device__ __forceinline__ float tanh2(float x) {
    // tanh(x) = 1 - 2/(exp(2x)+1); saturates correctly at +/-inf, no NaN
    return 1.f - 2.f * __builtin_amdgcn_rcpf(1.f + __expf(2.f * x));
}
// LDS-only barrier that does NOT drain vmcnt.
// v5 post-mortem: the old form (asm "waitcnt lgkmcnt(0); s_barrier" ::: "memory")
// carried a memory clobber -> SIInsertWaitcnts conservatively emitted
// s_waitcnt vmcnt(0) before the INLINEASM every step, draining the entire
// gate prefetch queue -> full scattered-load latency exposed per step
// (~3340 cy/step, all pipes <5% busy, insensitive to prefetch depth).
// New form: raw s_barrier builtin (no implicit drain) + bare lgkmcnt(0) asm
// (no clobbers -> no forced vmcnt wait). sched_barrier(0) on both sides
// (a) pins ds_write -> lgkmcnt(0) -> s_barrier ordering (cross-wave
// visibility of h_pre) and (b) splits scheduling regions so tail-issued
// prefetch loads cannot be sunk toward their use.
__device__ __forceinline__ void bar_lds() {
    __builtin_amdgcn_sched_barrier(0);
    __asm__ volatile("s_waitcnt lgkmcnt(0)");
    __builtin_amdgcn_s_barrier();
    __builtin_amdgcn_sched_barrier(0);
}

// ---------------------------------------------------------------------------
// Kernel 0: convert Wih, Wd to bf16; fold bhh_{r,z} into bih -> bihc.
// ---------------------------------------------------------------------------
__global__ __launch_bounds__(256) void k_convert(
    const float* __restrict__ Wih, const float* __restrict__ Wd,
    const float* __restrict__ bih, const float* __restrict__ bhh,
    ushort* __restrict__ wih_b, ushort* __restrict__ wd_b,
    float* __restrict__ bihc)
{
    int i = blockIdx.x * 256 + threadIdx.x;
    if (i < NG * KI) wih_b[i] = f2bf(Wih[i]);
    if (i < H_ * P_) wd_b[i]  = f2bf(Wd[i]);
    if (i < NG) bihc[i] = bih[i] + (i < 2 * H_ ? bhh[i] : 0.f);
}

// ---------------------------------------------------------------------------
// Kernel 1: fused elementwise + GEMM (MFMA bf16 16x16x32). [unchanged]
// ---------------------------------------------------------------------------
#define SA 392   // padded LDS row stride in bf16 elems (also >= 384 for staging)

__global__ __launch_bounds__(256, 2) void k_gemm(
    const float* __restrict__ X, const float* __restrict__ M,
    const float* __restrict__ DT, const float* __restrict__ xmean,
    const ushort* __restrict__ wih_b, const ushort* __restrict__ wd_b,
    const float* __restrict__ bih, const float* __restrict__ bd,
    ushort* __restrict__ gi_ws, ushort* __restrict__ htil_ws,
    float* __restrict__ delta_ws)
{
    __shared__ __align__(16) ushort sA[64 * SA];   // 50176 B; reused for staging
    const int tid = threadIdx.x;
    const long r0 = (long)blockIdx.x * 64;

    // ---- build A tile (64 rows x [x_dec|m|x_hat]) + delta (coalesced f32) ----
    #pragma unroll 4
    for (int i = 0; i < 32; ++i) {
        int idx = i * 256 + tid;
        int rl = idx >> 7, k = idx & 127;
        long g = (r0 + rl) * 128 + k;
        float x = X[g], m = M[g], dt = DT[g], xm = xmean[k];
        float delta = 1.f / (1.f + __expf(dt));   // sigmoid(-dt)
        float xh = m * x + (1.f - m) * xm;
        float xd = m * x + (1.f - m) * (delta * xh + (1.f - delta) * xm);
        sA[rl * SA + k]       = f2bf(xd);
        sA[rl * SA + 128 + k] = f2bf(m);
        sA[rl * SA + 256 + k] = f2bf(xh);
        delta_ws[g] = delta;
    }
    __syncthreads();

    const int wv   = tid >> 6;        // wave 0..3 -> gi col slice [96w,96w+96)
    const int lane = tid & 63;
    const int l16  = lane & 15;       // A row idx / B col idx / C col idx
    const int q    = lane >> 4;       // quad: A k-offset q*8 / C rows q*4+reg

    // ---- gi: acc[rt][nt], rt = row-tile (16 rows), nt = col-tile in slice ----
    f32x4 acc[4][6];
    #pragma unroll
    for (int rt = 0; rt < 4; ++rt)
        #pragma unroll
        for (int nt = 0; nt < 6; ++nt) acc[rt][nt] = (f32x4){0.f, 0.f, 0.f, 0.f};

    const int nb = 96 * wv;
    #pragma unroll
    for (int ks = 0; ks < 8; ++ks) {
        short8 a[4];
        #pragma unroll
        for (int rt = 0; rt < 4; ++rt)
            a[rt] = *(const short8*)&sA[(rt * 16 + l16) * SA + ks * 32 + q * 8];
        #pragma unroll
        for (int nt = 0; nt < 6; ++nt) {
            const short8 b = *(const short8*)&wih_b[(size_t)(nb + nt * 16 + l16) * KI + ks * 32 + q * 8];
            #pragma unroll
            for (int rt = 0; rt < 4; ++rt)
                acc[rt][nt] = __builtin_amdgcn_mfma_f32_16x16x32_bf16(a[rt], b, acc[rt][nt], 0, 0, 0);
        }
    }

    // ---- htil: acc2[rt][nt2], col slice [32w,32w+32), K=128 (A cols 256+) ----
    f32x4 acc2[4][2];
    #pragma unroll
    for (int rt = 0; rt < 4; ++rt)
        #pragma unroll
        for (int nt = 0; nt < 2; ++nt) acc2[rt][nt] = (f32x4){0.f, 0.f, 0.f, 0.f};

    const int nb2 = 32 * wv;
    #pragma unroll
    for (int ks = 0; ks < 4; ++ks) {
        short8 a[4];
        #pragma unroll
        for (int rt = 0; rt < 4; ++rt)
            a[rt] = *(const short8*)&sA[(rt * 16 + l16) * SA + 256 + ks * 32 + q * 8];
        #pragma unroll
        for (int nt = 0; nt < 2; ++nt) {
            const short8 b = *(const short8*)&wd_b[(size_t)(nb2 + nt * 16 + l16) * P_ + ks * 32 + q * 8];
            #pragma unroll
            for (int rt = 0; rt < 4; ++rt)
                acc2[rt][nt] = __builtin_amdgcn_mfma_f32_16x16x32_bf16(a[rt], b, acc2[rt][nt], 0, 0, 0);
        }
    }

    __syncthreads();   // all sA reads done; safe to overwrite with staging

    // ---- stage gi (bf16, [row][n] unpadded 64x384) into sA region ----
    ushort* sOut = sA;
    #pragma unroll
    for (int nt = 0; nt < 6; ++nt) {
        const int n = nb + nt * 16 + l16;
        const float bi = bih[n];
        #pragma unroll
        for (int rt = 0; rt < 4; ++rt) {
            #pragma unroll
            for (int reg = 0; reg < 4; ++reg) {
                int row = rt * 16 + q * 4 + reg;
                sOut[row * NG + n] = f2bf(acc[rt][nt][reg] + bi);
            }
        }
    }
    __syncthreads();

    // ---- coalesced contiguous store: 64*384 bf16 = 3072 uint4 ----
    {
        uint4* dst = (uint4*)(gi_ws + (size_t)r0 * NG);
        const uint4* src = (const uint4*)sOut;
        #pragma unroll
        for (int i = 0; i < 12; ++i) dst[tid + 256 * i] = src[tid + 256 * i];
    }
    __syncthreads();   // uint4 LDS reads retired; safe to restage

    // ---- stage htil (bf16, [row][n] 64x128) ----
    #pragma unroll
    for (int nt = 0; nt < 2; ++nt) {
        const int n = nb2 + nt * 16 + l16;
        const float bi = bd[n];
        #pragma unroll
        for (int rt = 0; rt < 4; ++rt) {
            #pragma unroll
            for (int reg = 0; reg < 4; ++reg) {
                int row = rt * 16 + q * 4 + reg;
                sOut[row * P_ + n] = f2bf(tanhf_fast(acc2[rt][nt][reg] + bi));
            }
        }
    }
    __syncthreads();

    // ---- coalesced store: 64*128 bf16 = 1024 uint4 ----
    {
        uint4* dst = (uint4*)(htil_ws + (size_t)r0 * P_);
        const uint4* src = (const uint4*)sOut;
        #pragma unroll
        for (int i = 0; i < 4; ++i) dst[tid + 256 * i] = src[tid + 256 * i];
    }
}

// ---------------------------------------------------------------------------
// Kernel 2: recurrent scan v6 — MFMA-batched, 4-deep prefetch rotation,
//   vmcnt-preserving barrier (see bar_lds comment).
// ---------------------------------------------------------------------------

#define DECLB(PFX) uint2 PFX##_r0, PFX##_r1, PFX##_z0, PFX##_z1,            \
                         PFX##_n0, PFX##_n1, PFX##_h0, PFX##_h1;            \
                   float4 PFX##_d0, PFX##_d1;

#define LOADG(PFX, T) if (act) {                                            \
    const ushort* gp = gptr + (size_t)(T) * NG;                             \
    const ushort* hp = hptr + (size_t)(T) * P_;                             \
    const float*  dp = dptr + (size_t)(T) * P_;                             \
    PFX##_r0 = *(const uint2*)(gp + j0);                                    \
    PFX##_r1 = *(const uint2*)(gp + j0 + 16);                               \
    PFX##_z0 = *(const uint2*)(gp + 128 + j0);                              \
    PFX##_z1 = *(const uint2*)(gp + 128 + j0 + 16);                         \
    PFX##_n0 = *(const uint2*)(gp + 256 + j0);                              \
    PFX##_n1 = *(const uint2*)(gp + 256 + j0 + 16);                         \
    PFX##_h0 = *(const uint2*)(hp + j0);                                    \
    PFX##_h1 = *(const uint2*)(hp + j0 + 16);                               \
    PFX##_d0 = *(const float4*)(dp + j0);                                   \
    PFX##_d1 = *(const float4*)(dp + j0 + 16);                              \
}

#define STEP(T, BC, BN, PC, PN) {                                           \
    bar_lds();                                                              \
    f16x8 bf[4];                                                            \
    _Pragma("unroll")                                                       \
    for (int ks = 0; ks < 4; ++ks)                                          \
        bf[ks] = *(const f16x8*)&h_lds[PC][bb][ks * 32 + q * 8];            \
    f32x4 ac[3][2];                                                         \
    ac[0][0] = (f32x4){bflo(BC##_r0.x), bfhi(BC##_r0.x), bflo(BC##_r0.y), bfhi(BC##_r0.y)}; \
    ac[0][1] = (f32x4){bflo(BC##_r1.x), bfhi(BC##_r1.x), bflo(BC##_r1.y), bfhi(BC##_r1.y)}; \
    ac[1][0] = (f32x4){bflo(BC##_z0.x), bfhi(BC##_z0.x), bflo(BC##_z0.y), bfhi(BC##_z0.y)}; \
    ac[1][1] = (f32x4){bflo(BC##_z1.x), bfhi(BC##_z1.x), bflo(BC##_z1.y), bfhi(BC##_z1.y)}; \
    ac[2][0] = (f32x4){bhn[0][0], bhn[0][1], bhn[0][2], bhn[0][3]};         \
    ac[2][1] = (f32x4){bhn[1][0], bhn[1][1], bhn[1][2], bhn[1][3]};         \
    _Pragma("unroll")                                                       \
    for (int ks = 0; ks < 4; ++ks) {                                        \
        _Pragma("unroll")                                                   \
        for (int g = 0; g < 3; ++g) {                                       \
            ac[g][0] = __builtin_amdgcn_mfma_f32_16x16x32_f16(aF[g][0][ks], bf[ks], ac[g][0], 0, 0, 0); \
            ac[g][1] = __builtin_amdgcn_mfma_f32_16x16x32_f16(aF[g][1][ks], bf[ks], ac[g][1], 0, 0, 0); \
        }                                                                   \
    }                                                                       \
    if (act) {                                                              \
        _Pragma("unroll")                                                   \
        for (int jt = 0; jt < 2; ++jt) {                                    \
            uint2 gnv = jt ? BC##_n1 : BC##_n0;                             \
            uint2 htv = jt ? BN##_h1 : BN##_h0;                             \
            float4 dlv = jt ? BN##_d1 : BN##_d0;                            \
            float gn_[4] = {bflo(gnv.x), bfhi(gnv.x), bflo(gnv.y), bfhi(gnv.y)}; \
            float ht_[4] = {bflo(htv.x), bfhi(htv.x), bflo(htv.y), bfhi(htv.y)}; \
            float dl_[4] = {dlv.x, dlv.y, dlv.z, dlv.w};                    \
            float hnv[4];                                                   \
            _Pragma("unroll")                                               \
            for (int r = 0; r < 4; ++r) {                                   \
                float rg = sigf2(ac[0][jt][r]);                             \
                float zg = sigf2(ac[1][jt][r]);                             \
                float np = gn_[r] + rg * ac[2][jt][r];                      \
                float ng = tanh2(np);                                       \
                float hn = ng + zg * (hpre[jt][r] - ng);                    \
                hnv[r] = hn;                                                \
                hpre[jt][r] = ht_[r] + dl_[r] * (hn - ht_[r]);              \
            }                                                               \
            *(float4*)&Hraw[(rowb + (T)) * P_ + j0 + jt * 16] =             \
                make_float4(hnv[0], hnv[1], hnv[2], hnv[3]);                \
            f16 p0 = (f16)hpre[jt][0], p1 = (f16)hpre[jt][1],               \
                p2 = (f16)hpre[jt][2], p3 = (f16)hpre[jt][3];               \
            union { f16 h[4]; uint2 u; } pk = {{p0, p1, p2, p3}};           \
            *(uint2*)&h_lds[PN][bb][j0 + jt * 16] = pk.u;                   \
        }                                                                   \
    }                                                                       \
    if ((T) + 4 < TR) LOADG(BC, (T) + 4);                                   \
}

__global__ __launch_bounds__(256, 1) void k_scan(
    const ushort* __restrict__ gi_ws, const ushort* __restrict__ htil_ws,
    const float* __restrict__ delta_ws, const float* __restrict__ Whh,
    const float* __restrict__ bhh, float* __restrict__ Hraw)
{
    __shared__ __align__(16) f16 h_lds[2][16][136];   // 8704 B; +8 pad/row

    const int tid  = threadIdx.x;
    const int w    = tid >> 6;          // wave 0..3 -> j slice [32w, 32w+32)
    const int lane = tid & 63;
    const int bb   = lane & 15;         // B col = batch (0..7 real)
    const int q    = lane >> 4;         // k-chunk / C row group
    const bool act = bb < NB;
    const int bbw  = bb & (NB - 1);
    const int b0   = blockIdx.x * NB;
    const int j0   = w * 32 + q * 4;    // jt adds +16

    // zero LDS (covers parity-1 and the unused batch cols 8..15)
    for (int i = tid; i < 2 * 16 * 136; i += 256) ((f16*)h_lds)[i] = (f16)0.f;

    // Whh A-fragments: load f32, convert to f16 in-register.
    f16x8 aF[3][2][4];
    #pragma unroll
    for (int g = 0; g < 3; ++g)
        #pragma unroll
        for (int jt = 0; jt < 2; ++jt) {
            const float* wr = Whh + (size_t)(g * 128 + w * 32 + jt * 16 + bb) * 128;
            #pragma unroll
            for (int ks = 0; ks < 4; ++ks) {
                float4 a = *(const float4*)(wr + ks * 32 + q * 8);
                float4 c = *(const float4*)(wr + ks * 32 + q * 8 + 4);
                f16x8 v;
                v[0] = (f16)a.x; v[1] = (f16)a.y; v[2] = (f16)a.z; v[3] = (f16)a.w;
                v[4] = (f16)c.x; v[5] = (f16)c.y; v[6] = (f16)c.z; v[7] = (f16)c.w;
                aF[g][jt][ks] = v;
            }
        }

    float bhn[2][4];
    #pragma unroll
    for (int jt = 0; jt < 2; ++jt)
        #pragma unroll
        for (int r = 0; r < 4; ++r)
            bhn[jt][r] = bhh[256 + j0 + jt * 16 + r];

    const long rowb = (long)(b0 + bbw) * TR;
    const ushort* gptr = gi_ws   + rowb * NG;
    const ushort* hptr = htil_ws + rowb * P_;
    const float*  dptr = delta_ws + rowb * P_;

    DECLB(gA) DECLB(gB) DECLB(gC) DECLB(gD)

    LOADG(gA, 0);
    LOADG(gB, 1);
    LOADG(gC, 2);
    LOADG(gD, 3);

    float hpre[2][4] = {{0.f, 0.f, 0.f, 0.f}, {0.f, 0.f, 0.f, 0.f}};

    __syncthreads();   // zero-init visible before h_pre(0) writes

    // h_pre(0) = (1 - d0) * htil0   (h(-1) = 0)
    if (act) {
        #pragma unroll
        for (int jt = 0; jt < 2; ++jt) {
            uint2 htv = jt ? gA_h1 : gA_h0;
            float4 dlv = jt ? gA_d1 : gA_d0;
            float ht_[4] = {bflo(htv.x), bfhi(htv.x), bflo(htv.y), bfhi(htv.y)};
            float dl_[4] = {dlv.x, dlv.y, dlv.z, dlv.w};
            #pragma unroll
            for (int r = 0; r < 4; ++r)
                hpre[jt][r] = ht_[r] - dl_[r] * ht_[r];
            f16 p0 = (f16)hpre[jt][0], p1 = (f16)hpre[jt][1],
                p2 = (f16)hpre[jt][2], p3 = (f16)hpre[jt][3];
            union { f16 h[4]; uint2 u; } pk = {{p0, p1, p2, p3}};
            *(uint2*)&h_lds[0][bb][j0 + jt * 16] = pk.u;
        }
    }

    for (int t = 0; t < TR; t += 4) {
        STEP(t,     gA, gB, 0, 1);
        STEP(t + 1, gB, gC, 1, 0);
        STEP(t + 2, gC, gD, 0, 1);
        STEP(t + 3, gD, gA, 1, 0);
    }
}

// ---------------------------------------------------------------------------
// Kernel 3: head. [unchanged]
// ---------------------------------------------------------------------------
__global__ __launch_bounds__(256) void k_head(
    const float* __restrict__ Hraw, const float* __restrict__ STD,
    const float* __restrict__ Z, const int* __restrict__ idx_map,
    const float* __restrict__ W1, const float* __restrict__ b1,
    const float* __restrict__ W2,
    float* __restrict__ eta, float* __restrict__ Hagg,
    float* __restrict__ mask_out)
{
    __shared__ float sW1[HH * FDIM];
    __shared__ float sb1[HH], sW2[HH];
    __shared__ float spart[TA][4];

    const int tid = threadIdx.x, b = blockIdx.x;
    for (int i = tid; i < HH * FDIM; i += 256) sW1[i] = W1[i];
    if (tid < HH) { sb1[tid] = b1[tid]; sW2[tid] = W2[tid]; }
    __syncthreads();

    const int s = tid >> 2, p = tid & 3;
    const int idx = idx_map[b * TA + s];
    const int valid = idx >= 0;
    const int tt = valid ? idx : 0;
    const float* hrow = Hraw + ((long)b * TR + tt) * H_;

    float acc[16];
    #pragma unroll
    for (int uu = 0; uu < 16; ++uu) acc[uu] = sb1[p * 16 + uu];

    for (int f = 0; f < FDIM; ++f) {
        float feat;
        if (f < H_)              feat = valid ? hrow[f] : 0.f;
        else if (f < H_ + PSTD)  feat = STD[((long)b * TA + s) * PSTD + (f - H_)];
        else                     feat = Z[b * PSTAT + (f - H_ - PSTD)];
        #pragma unroll
        for (int uu = 0; uu < 16; ++uu)
            acc[uu] += feat * sW1[(p * 16 + uu) * FDIM + f];
    }

    float pe = 0.f;
    #pragma unroll
    for (int uu = 0; uu < 16; ++uu) {
        float a = acc[uu];
        pe += (a > 0.f ? a : 0.f) * sW2[p * 16 + uu];
    }
    spart[s][p] = pe;

    for (int e = 0; e < 32; ++e) {
        int ee = p * 32 + e;
        Hagg[((long)b * TA + s) * H_ + ee] = valid ? hrow[ee] : 0.f;
    }
    if (p == 0) mask_out[b * TA + s] = valid ? 1.f : 0.f;

    __syncthreads();
    if (tid < TA)
        eta[b * TA + tid] = spart[tid][0] + spart[tid][1] + spart[tid][2] + spart[tid][3];
}

// ---------------------------------------------------------------------------
extern "C" void kernel_launch(void* const* d_in, const int* in_sizes, int n_in,
                              void* d_out, int out_size, void* d_ws, size_t ws_size,
                              hipStream_t stream)
{
    const float* X     = (const float*)d_in[0];
    const float* M     = (const float*)d_in[1];
    const float* DT    = (const float*)d_in[2];
    const float* STD   = (const float*)d_in[3];
    const float* Z     = (const float*)d_in[4];
    const int*   idxm  = (const int*)  d_in[5];
    const float* xmean = (const float*)d_in[6];
    const float* Wd    = (const float*)d_in[7];
    const float* bd    = (const float*)d_in[8];
    const float* Wih   = (const float*)d_in[9];
    const float* bih   = (const float*)d_in[10];
    const float* Whh   = (const float*)d_in[11];
    const float* bhh   = (const float*)d_in[12];
    const float* W1    = (const float*)d_in[13];
    const float* b1    = (const float*)d_in[14];
    const float* W2    = (const float*)d_in[15];

    const long RROWS = (long)B_ * TR;   // 131072
    char* ws = (char*)d_ws;
    size_t off = 0;
    ushort* gi_ws   = (ushort*)(ws + off); off += (size_t)RROWS * NG * 2;
    ushort* htil_ws = (ushort*)(ws + off); off += (size_t)RROWS * P_ * 2;
    float*  delta_ws= (float*) (ws + off); off += (size_t)RROWS * P_ * 4;
    ushort* wih_b   = (ushort*)(ws + off); off += (size_t)NG * KI * 2;
    ushort* wd_b    = (ushort*)(ws + off); off += (size_t)H_ * P_ * 2;
    float*  bihc    = (float*) (ws + off); off += (size_t)NG * 4;

    float* out   = (float*)d_out;
    float* eta   = out;                                  // [256,64]
    float* Hraw  = out + 16384;                          // [256,512,128]
    float* Hagg  = out + 16384 + (long)B_ * TR * H_;     // [256,64,128]
    float* maskO = Hagg + (long)B_ * TA * H_;            // [256,64]

    hipLaunchKernelGGL(k_convert, dim3(384), dim3(256), 0, stream,
                       Wih, Wd, bih, bhh, wih_b, wd_b, bihc);
    hipLaunchKernelGGL(k_gemm, dim3(2048), dim3(256), 0, stream,
                       X, M, DT, xmean, wih_b, wd_b, bihc, bd,
                       gi_ws, htil_ws, delta_ws);
    hipLaunchKernelGGL(k_scan, dim3(NSCAN), dim3(256), 0, stream,
                       gi_ws, htil_ws, delta_ws, Whh, bhh, Hraw);
    hipLaunchKernelGGL(k_head, dim3(256), dim3(256), 0, stream,
                       Hraw, STD, Z, idxm, W1, b1, W2, eta, Hagg, maskO);
}

// Round 5
// 862.067 us; speedup vs baseline: 1.2618x; 1.2586x over previous
//
#include <hip/hip_runtime.h>
#include <hip/hip_bf16.h>
#include <hip/hip_fp16.h>

// Problem constants
#define B_    256
#define TR    512
#define P_    128
#define H_    128
#define NG    384      // 3*H
#define KI    256      // 2*P
#define TA    64
#define PSTD  32
#define PSTAT 16
#define HH    64       // HEAD_H
#define FDIM  176      // H + P_STD + P_STATIC

#define NB    8            // batches per scan block (MFMA N-cols used)
#define NSCAN (B_/NB)      // 32 scan blocks

typedef __attribute__((ext_vector_type(8))) short short8;
typedef __attribute__((ext_vector_type(4))) float f32x4;
typedef _Float16 f16;
typedef __attribute__((ext_vector_type(8))) _Float16 f16x8;

// ---- helpers ----
__device__ __forceinline__ float bf2f(ushort u) {
    union { uint i; float f; } v; v.i = ((uint)u) << 16; return v.f;
}
__device__ __forceinline__ ushort f2bf(float f) {
    union { float f; uint u; } v; v.f = f;
    uint u = v.u;
    uint r = (u + 0x7fffu + ((u >> 16) & 1u)) >> 16;  // RTNE
    return (ushort)r;
}
__device__ __forceinline__ float bflo(uint u) {
    union { uint i; float f; } v; v.i = u << 16; return v.f;
}
__device__ __forceinline__ float bfhi(uint u) {
    union { uint i; float f; } v; v.i = u & 0xffff0000u; return v.f;
}
__device__ __forceinline__ float tanhf_fast(float x) {
    float ax = fabsf(x);
    float e = __expf(-2.f * ax);
    float r = (1.f - e) / (1.f + e);
    return copysignf(r, x);
}
// branch-free scan transcendentals (v_exp + v_rcp)
__device__ __forceinline__ float sigf2(float x) {
    return __builtin_amdgcn_rcpf(1.f + __expf(-x));
}
__device__ __forceinline__ float tanh2(float x) {
    // tanh(x) = 1 - 2/(exp(2x)+1); saturates correctly at +/-inf, no NaN
    return 1.f - 2.f * __builtin_amdgcn_rcpf(1.f + __expf(2.f * x));
}
// LDS-only barrier that does NOT drain vmcnt (raw s_barrier; lgkm wait only).
__device__ __forceinline__ void bar_lds() {
    __builtin_amdgcn_sched_barrier(0);
    __asm__ volatile("s_waitcnt lgkmcnt(0)");
    __builtin_amdgcn_s_barrier();
    __builtin_amdgcn_sched_barrier(0);
}

// ---------------------------------------------------------------------------
// Kernel 0: convert Wih, Wd to bf16; fold bhh_{r,z} into bih -> bihc.
// ---------------------------------------------------------------------------
__global__ __launch_bounds__(256) void k_convert(
    const float* __restrict__ Wih, const float* __restrict__ Wd,
    const float* __restrict__ bih, const float* __restrict__ bhh,
    ushort* __restrict__ wih_b, ushort* __restrict__ wd_b,
    float* __restrict__ bihc)
{
    int i = blockIdx.x * 256 + threadIdx.x;
    if (i < NG * KI) wih_b[i] = f2bf(Wih[i]);
    if (i < H_ * P_) wd_b[i]  = f2bf(Wd[i]);
    if (i < NG) bihc[i] = bih[i] + (i < 2 * H_ ? bhh[i] : 0.f);
}

// ---------------------------------------------------------------------------
// Kernel 1: fused elementwise + GEMM (MFMA bf16 16x16x32). [unchanged]
// ---------------------------------------------------------------------------
#define SA 392   // padded LDS row stride in bf16 elems (also >= 384 for staging)

__global__ __launch_bounds__(256, 2) void k_gemm(
    const float* __restrict__ X, const float* __restrict__ M,
    const float* __restrict__ DT, const float* __restrict__ xmean,
    const ushort* __restrict__ wih_b, const ushort* __restrict__ wd_b,
    const float* __restrict__ bih, const float* __restrict__ bd,
    ushort* __restrict__ gi_ws, ushort* __restrict__ htil_ws,
    float* __restrict__ delta_ws)
{
    __shared__ __align__(16) ushort sA[64 * SA];   // 50176 B; reused for staging
    const int tid = threadIdx.x;
    const long r0 = (long)blockIdx.x * 64;

    // ---- build A tile (64 rows x [x_dec|m|x_hat]) + delta (coalesced f32) ----
    #pragma unroll 4
    for (int i = 0; i < 32; ++i) {
        int idx = i * 256 + tid;
        int rl = idx >> 7, k = idx & 127;
        long g = (r0 + rl) * 128 + k;
        float x = X[g], m = M[g], dt = DT[g], xm = xmean[k];
        float delta = 1.f / (1.f + __expf(dt));   // sigmoid(-dt)
        float xh = m * x + (1.f - m) * xm;
        float xd = m * x + (1.f - m) * (delta * xh + (1.f - delta) * xm);
        sA[rl * SA + k]       = f2bf(xd);
        sA[rl * SA + 128 + k] = f2bf(m);
        sA[rl * SA + 256 + k] = f2bf(xh);
        delta_ws[g] = delta;
    }
    __syncthreads();

    const int wv   = tid >> 6;        // wave 0..3 -> gi col slice [96w,96w+96)
    const int lane = tid & 63;
    const int l16  = lane & 15;       // A row idx / B col idx / C col idx
    const int q    = lane >> 4;       // quad: A k-offset q*8 / C rows q*4+reg

    // ---- gi: acc[rt][nt], rt = row-tile (16 rows), nt = col-tile in slice ----
    f32x4 acc[4][6];
    #pragma unroll
    for (int rt = 0; rt < 4; ++rt)
        #pragma unroll
        for (int nt = 0; nt < 6; ++nt) acc[rt][nt] = (f32x4){0.f, 0.f, 0.f, 0.f};

    const int nb = 96 * wv;
    #pragma unroll
    for (int ks = 0; ks < 8; ++ks) {
        short8 a[4];
        #pragma unroll
        for (int rt = 0; rt < 4; ++rt)
            a[rt] = *(const short8*)&sA[(rt * 16 + l16) * SA + ks * 32 + q * 8];
        #pragma unroll
        for (int nt = 0; nt < 6; ++nt) {
            const short8 b = *(const short8*)&wih_b[(size_t)(nb + nt * 16 + l16) * KI + ks * 32 + q * 8];
            #pragma unroll
            for (int rt = 0; rt < 4; ++rt)
                acc[rt][nt] = __builtin_amdgcn_mfma_f32_16x16x32_bf16(a[rt], b, acc[rt][nt], 0, 0, 0);
        }
    }

    // ---- htil: acc2[rt][nt2], col slice [32w,32w+32), K=128 (A cols 256+) ----
    f32x4 acc2[4][2];
    #pragma unroll
    for (int rt = 0; rt < 4; ++rt)
        #pragma unroll
        for (int nt = 0; nt < 2; ++nt) acc2[rt][nt] = (f32x4){0.f, 0.f, 0.f, 0.f};

    const int nb2 = 32 * wv;
    #pragma unroll
    for (int ks = 0; ks < 4; ++ks) {
        short8 a[4];
        #pragma unroll
        for (int rt = 0; rt < 4; ++rt)
            a[rt] = *(const short8*)&sA[(rt * 16 + l16) * SA + 256 + ks * 32 + q * 8];
        #pragma unroll
        for (int nt = 0; nt < 2; ++nt) {
            const short8 b = *(const short8*)&wd_b[(size_t)(nb2 + nt * 16 + l16) * P_ + ks * 32 + q * 8];
            #pragma unroll
            for (int rt = 0; rt < 4; ++rt)
                acc2[rt][nt] = __builtin_amdgcn_mfma_f32_16x16x32_bf16(a[rt], b, acc2[rt][nt], 0, 0, 0);
        }
    }

    __syncthreads();   // all sA reads done; safe to overwrite with staging

    // ---- stage gi (bf16, [row][n] unpadded 64x384) into sA region ----
    ushort* sOut = sA;
    #pragma unroll
    for (int nt = 0; nt < 6; ++nt) {
        const int n = nb + nt * 16 + l16;
        const float bi = bih[n];
        #pragma unroll
        for (int rt = 0; rt < 4; ++rt) {
            #pragma unroll
            for (int reg = 0; reg < 4; ++reg) {
                int row = rt * 16 + q * 4 + reg;
                sOut[row * NG + n] = f2bf(acc[rt][nt][reg] + bi);
            }
        }
    }
    __syncthreads();

    // ---- coalesced contiguous store: 64*384 bf16 = 3072 uint4 ----
    {
        uint4* dst = (uint4*)(gi_ws + (size_t)r0 * NG);
        const uint4* src = (const uint4*)sOut;
        #pragma unroll
        for (int i = 0; i < 12; ++i) dst[tid + 256 * i] = src[tid + 256 * i];
    }
    __syncthreads();   // uint4 LDS reads retired; safe to restage

    // ---- stage htil (bf16, [row][n] 64x128) ----
    #pragma unroll
    for (int nt = 0; nt < 2; ++nt) {
        const int n = nb2 + nt * 16 + l16;
        const float bi = bd[n];
        #pragma unroll
        for (int rt = 0; rt < 4; ++rt) {
            #pragma unroll
            for (int reg = 0; reg < 4; ++reg) {
                int row = rt * 16 + q * 4 + reg;
                sOut[row * P_ + n] = f2bf(tanhf_fast(acc2[rt][nt][reg] + bi));
            }
        }
    }
    __syncthreads();

    // ---- coalesced store: 64*128 bf16 = 1024 uint4 ----
    {
        uint4* dst = (uint4*)(htil_ws + (size_t)r0 * P_);
        const uint4* src = (const uint4*)sOut;
        #pragma unroll
        for (int i = 0; i < 4; ++i) dst[tid + 256 * i] = src[tid + 256 * i];
    }
}

// ---------------------------------------------------------------------------
// Kernel 2: recurrent scan v7 — MFMA-batched, 8 waves, spill-free.
//   v6 post-mortem: VGPR demand ~270 (aF 96 + 4 bufs 96 + bf/ac/misc) vs
//   144-160 allocated -> ~100 VGPRs spilled to scratch. Per-step scratch
//   reload chain (~200-400cy L2 latency x ~25 reloads) explains the
//   ~3340 cy/step stall, <5% pipe utilization, and the total insensitivity
//   to barrier semantics and prefetch depth.
//   v7: 512 threads (8 waves), each wave owns a 16-wide j-slice:
//     aF 3x4xf16x8 = 48 VGPR, buffers 4x12 = 48, ac 12 -> demand ~175.
//     __launch_bounds__(512,2) -> 256-VGPR cap, fits with no spills.
//   Same MFMA trick: col=lane&15=batch, row=q*4+reg=j; A-row=lane&15.
// ---------------------------------------------------------------------------

#define DECLB(PFX) uint2 PFX##_r, PFX##_z, PFX##_n, PFX##_h; float4 PFX##_d;

#define LOADG(PFX, T) if (act) {                                            \
    const ushort* gp = gptr + (size_t)(T) * NG;                             \
    PFX##_r = *(const uint2*)(gp + j0);                                     \
    PFX##_z = *(const uint2*)(gp + 128 + j0);                               \
    PFX##_n = *(const uint2*)(gp + 256 + j0);                               \
    PFX##_h = *(const uint2*)(hptr + (size_t)(T) * P_ + j0);                \
    PFX##_d = *(const float4*)(dptr + (size_t)(T) * P_ + j0);               \
}

#define STEP(T, BC, BN, PC, PN) {                                           \
    bar_lds();                                                              \
    f16x8 bf[4];                                                            \
    _Pragma("unroll")                                                       \
    for (int ks = 0; ks < 4; ++ks)                                          \
        bf[ks] = *(const f16x8*)&h_lds[PC][bb][ks * 32 + q * 8];            \
    f32x4 ac0, ac1, ac2;                                                    \
    ac0 = (f32x4){bflo(BC##_r.x), bfhi(BC##_r.x), bflo(BC##_r.y), bfhi(BC##_r.y)}; \
    ac1 = (f32x4){bflo(BC##_z.x), bfhi(BC##_z.x), bflo(BC##_z.y), bfhi(BC##_z.y)}; \
    ac2 = (f32x4){bhn[0], bhn[1], bhn[2], bhn[3]};                          \
    _Pragma("unroll")                                                       \
    for (int ks = 0; ks < 4; ++ks) {                                        \
        ac0 = __builtin_amdgcn_mfma_f32_16x16x32_f16(aF[0][ks], bf[ks], ac0, 0, 0, 0); \
        ac1 = __builtin_amdgcn_mfma_f32_16x16x32_f16(aF[1][ks], bf[ks], ac1, 0, 0, 0); \
        ac2 = __builtin_amdgcn_mfma_f32_16x16x32_f16(aF[2][ks], bf[ks], ac2, 0, 0, 0); \
    }                                                                       \
    if (act) {                                                              \
        float gn_[4] = {bflo(BC##_n.x), bfhi(BC##_n.x), bflo(BC##_n.y), bfhi(BC##_n.y)}; \
        float ht_[4] = {bflo(BN##_h.x), bfhi(BN##_h.x), bflo(BN##_h.y), bfhi(BN##_h.y)}; \
        float dl_[4] = {BN##_d.x, BN##_d.y, BN##_d.z, BN##_d.w};            \
        float hnv[4];                                                       \
        _Pragma("unroll")                                                   \
        for (int r = 0; r < 4; ++r) {                                       \
            float rg = sigf2(ac0[r]);                                       \
            float zg = sigf2(ac1[r]);                                       \
            float np = gn_[r] + rg * ac2[r];                                \
            float ng = tanh2(np);                                           \
            float hn = ng + zg * (hpre[r] - ng);                            \
            hnv[r] = hn;                                                    \
            hpre[r] = ht_[r] + dl_[r] * (hn - ht_[r]);                      \
        }                                                                   \
        *(float4*)&Hraw[(rowb + (T)) * P_ + j0] =                           \
            make_float4(hnv[0], hnv[1], hnv[2], hnv[3]);                    \
        f16 p0 = (f16)hpre[0], p1 = (f16)hpre[1],                           \
            p2 = (f16)hpre[2], p3 = (f16)hpre[3];                           \
        union { f16 h[4]; uint2 u; } pk = {{p0, p1, p2, p3}};               \
        *(uint2*)&h_lds[PN][bb][j0] = pk.u;                                 \
    }                                                                       \
    if ((T) + 4 < TR) LOADG(BC, (T) + 4);                                   \
}

__global__ __launch_bounds__(512, 2) void k_scan(
    const ushort* __restrict__ gi_ws, const ushort* __restrict__ htil_ws,
    const float* __restrict__ delta_ws, const float* __restrict__ Whh,
    const float* __restrict__ bhh, float* __restrict__ Hraw)
{
    __shared__ __align__(16) f16 h_lds[2][16][136];   // 8704 B; +8 pad/row

    const int tid  = threadIdx.x;
    const int w    = tid >> 6;          // wave 0..7 -> j slice [16w, 16w+16)
    const int lane = tid & 63;
    const int bb   = lane & 15;         // A row / B col / C col = batch
    const int q    = lane >> 4;         // B k-chunk / C row group
    const bool act = bb < NB;
    const int bbw  = bb & (NB - 1);
    const int b0   = blockIdx.x * NB;
    const int j0   = w * 16 + q * 4;    // this lane's 4 output j's

    // zero LDS (covers parity-1 and the unused batch cols 8..15)
    for (int i = tid; i < 2 * 16 * 136; i += 512) ((f16*)h_lds)[i] = (f16)0.f;

    // Whh A-fragments: load f32, convert to f16 in-register.
    // A-row (within 16-tile) = lane&15 = bb; k-offset = q*8.
    f16x8 aF[3][4];
    #pragma unroll
    for (int g = 0; g < 3; ++g) {
        const float* wr = Whh + (size_t)(g * 128 + w * 16 + bb) * 128;
        #pragma unroll
        for (int ks = 0; ks < 4; ++ks) {
            float4 a = *(const float4*)(wr + ks * 32 + q * 8);
            float4 c = *(const float4*)(wr + ks * 32 + q * 8 + 4);
            f16x8 v;
            v[0] = (f16)a.x; v[1] = (f16)a.y; v[2] = (f16)a.z; v[3] = (f16)a.w;
            v[4] = (f16)c.x; v[5] = (f16)c.y; v[6] = (f16)c.z; v[7] = (f16)c.w;
            aF[g][ks] = v;
        }
    }

    float bhn[4];
    #pragma unroll
    for (int r = 0; r < 4; ++r) bhn[r] = bhh[256 + j0 + r];

    const long rowb = (long)(b0 + bbw) * TR;
    const ushort* gptr = gi_ws   + rowb * NG;
    const ushort* hptr = htil_ws + rowb * P_;
    const float*  dptr = delta_ws + rowb * P_;

    DECLB(gA) DECLB(gB) DECLB(gC) DECLB(gD)

    LOADG(gA, 0);
    LOADG(gB, 1);
    LOADG(gC, 2);
    LOADG(gD, 3);

    float hpre[4] = {0.f, 0.f, 0.f, 0.f};

    __syncthreads();   // zero-init visible before h_pre(0) writes

    // h_pre(0) = (1 - d0) * htil0   (h(-1) = 0)
    if (act) {
        float ht_[4] = {bflo(gA_h.x), bfhi(gA_h.x), bflo(gA_h.y), bfhi(gA_h.y)};
        float dl_[4] = {gA_d.x, gA_d.y, gA_d.z, gA_d.w};
        #pragma unroll
        for (int r = 0; r < 4; ++r)
            hpre[r] = ht_[r] - dl_[r] * ht_[r];
        f16 p0 = (f16)hpre[0], p1 = (f16)hpre[1],
            p2 = (f16)hpre[2], p3 = (f16)hpre[3];
        union { f16 h[4]; uint2 u; } pk = {{p0, p1, p2, p3}};
        *(uint2*)&h_lds[0][bb][j0] = pk.u;
    }

    for (int t = 0; t < TR; t += 4) {
        STEP(t,     gA, gB, 0, 1);
        STEP(t + 1, gB, gC, 1, 0);
        STEP(t + 2, gC, gD, 0, 1);
        STEP(t + 3, gD, gA, 1, 0);
    }
}

// ---------------------------------------------------------------------------
// Kernel 3: head. [unchanged]
// ---------------------------------------------------------------------------
__global__ __launch_bounds__(256) void k_head(
    const float* __restrict__ Hraw, const float* __restrict__ STD,
    const float* __restrict__ Z, const int* __restrict__ idx_map,
    const float* __restrict__ W1, const float* __restrict__ b1,
    const float* __restrict__ W2,
    float* __restrict__ eta, float* __restrict__ Hagg,
    float* __restrict__ mask_out)
{
    __shared__ float sW1[HH * FDIM];
    __shared__ float sb1[HH], sW2[HH];
    __shared__ float spart[TA][4];

    const int tid = threadIdx.x, b = blockIdx.x;
    for (int i = tid; i < HH * FDIM; i += 256) sW1[i] = W1[i];
    if (tid < HH) { sb1[tid] = b1[tid]; sW2[tid] = W2[tid]; }
    __syncthreads();

    const int s = tid >> 2, p = tid & 3;
    const int idx = idx_map[b * TA + s];
    const int valid = idx >= 0;
    const int tt = valid ? idx : 0;
    const float* hrow = Hraw + ((long)b * TR + tt) * H_;

    float acc[16];
    #pragma unroll
    for (int uu = 0; uu < 16; ++uu) acc[uu] = sb1[p * 16 + uu];

    for (int f = 0; f < FDIM; ++f) {
        float feat;
        if (f < H_)              feat = valid ? hrow[f] : 0.f;
        else if (f < H_ + PSTD)  feat = STD[((long)b * TA + s) * PSTD + (f - H_)];
        else                     feat = Z[b * PSTAT + (f - H_ - PSTD)];
        #pragma unroll
        for (int uu = 0; uu < 16; ++uu)
            acc[uu] += feat * sW1[(p * 16 + uu) * FDIM + f];
    }

    float pe = 0.f;
    #pragma unroll
    for (int uu = 0; uu < 16; ++uu) {
        float a = acc[uu];
        pe += (a > 0.f ? a : 0.f) * sW2[p * 16 + uu];
    }
    spart[s][p] = pe;

    for (int e = 0; e < 32; ++e) {
        int ee = p * 32 + e;
        Hagg[((long)b * TA + s) * H_ + ee] = valid ? hrow[ee] : 0.f;
    }
    if (p == 0) mask_out[b * TA + s] = valid ? 1.f : 0.f;

    __syncthreads();
    if (tid < TA)
        eta[b * TA + tid] = spart[tid][0] + spart[tid][1] + spart[tid][2] + spart[tid][3];
}

// ---------------------------------------------------------------------------
extern "C" void kernel_launch(void* const* d_in, const int* in_sizes, int n_in,
                              void* d_out, int out_size, void* d_ws, size_t ws_size,
                              hipStream_t stream)
{
    const float* X     = (const float*)d_in[0];
    const float* M     = (const float*)d_in[1];
    const float* DT    = (const float*)d_in[2];
    const float* STD   = (const float*)d_in[3];
    const float* Z     = (const float*)d_in[4];
    const int*   idxm  = (const int*)  d_in[5];
    const float* xmean = (const float*)d_in[6];
    const float* Wd    = (const float*)d_in[7];
    const float* bd    = (const float*)d_in[8];
    const float* Wih   = (const float*)d_in[9];
    const float* bih   = (const float*)d_in[10];
    const float* Whh   = (const float*)d_in[11];
    const float* bhh   = (const float*)d_in[12];
    const float* W1    = (const float*)d_in[13];
    const float* b1    = (const float*)d_in[14];
    const float* W2    = (const float*)d_in[15];

    const long RROWS = (long)B_ * TR;   // 131072
    char* ws = (char*)d_ws;
    size_t off = 0;
    ushort* gi_ws   = (ushort*)(ws + off); off += (size_t)RROWS * NG * 2;
    ushort* htil_ws = (ushort*)(ws + off); off += (size_t)RROWS * P_ * 2;
    float*  delta_ws= (float*) (ws + off); off += (size_t)RROWS * P_ * 4;
    ushort* wih_b   = (ushort*)(ws + off); off += (size_t)NG * KI * 2;
    ushort* wd_b    = (ushort*)(ws + off); off += (size_t)H_ * P_ * 2;
    float*  bihc    = (float*) (ws + off); off += (size_t)NG * 4;

    float* out   = (float*)d_out;
    float* eta   = out;                                  // [256,64]
    float* Hraw  = out + 16384;                          // [256,512,128]
    float* Hagg  = out + 16384 + (long)B_ * TR * H_;     // [256,64,128]
    float* maskO = Hagg + (long)B_ * TA * H_;            // [256,64]

    hipLaunchKernelGGL(k_convert, dim3(384), dim3(256), 0, stream,
                       Wih, Wd, bih, bhh, wih_b, wd_b, bihc);
    hipLaunchKernelGGL(k_gemm, dim3(2048), dim3(256), 0, stream,
                       X, M, DT, xmean, wih_b, wd_b, bihc, bd,
                       gi_ws, htil_ws, delta_ws);
    hipLaunchKernelGGL(k_scan, dim3(NSCAN), dim3(512), 0, stream,
                       gi_ws, htil_ws, delta_ws, Whh, bhh, Hraw);
    hipLaunchKernelGGL(k_head, dim3(256), dim3(256), 0, stream,
                       Hraw, STD, Z, idxm, W1, b1, W2, eta, Hagg, maskO);
}